// Round 8
// baseline (178.989 us; speedup 1.0000x reference)
//
#include <hip/hip_runtime.h>
#include <hip/hip_bf16.h>
#include <math.h>

#define DEVFN __device__ __forceinline__

typedef __attribute__((ext_vector_type(8))) __bf16 bf16x8;
typedef __attribute__((ext_vector_type(8))) short s16x8;
typedef __attribute__((ext_vector_type(4))) float f32x4;
typedef __attribute__((ext_vector_type(4))) unsigned int u32x4;

constexpr int Tt    = 2048;
constexpr int INt   = 128;
constexpr int Ht    = 256;
constexpr int OUTt  = 8;
constexpr int TT    = 32;           // time tile
constexpr int NTILE = Tt / TT;      // 64

union Frag {
  s16x8 s;
  bf16x8 b;
  u32x4 u;
};

DEVFN unsigned short f2bf(float f) {
  unsigned int u = __builtin_bit_cast(unsigned int, f);
  u += 0x7fffu + ((u >> 16) & 1u);   // round-to-nearest-even
  return (unsigned short)(u >> 16);
}

DEVFN unsigned int pack2(float lo, float hi) {
  return (unsigned int)f2bf(lo) | ((unsigned int)f2bf(hi) << 16);
}

typedef __attribute__((address_space(3))) unsigned int lds_u32;
typedef const __attribute__((address_space(1))) unsigned int glb_u32;

// HBM -> LDS DMA, 16B/lane, LDS dest = uniform base + lane*16 (linear).
DEVFN void dma16(const float* g, const float* l) {
  __builtin_amdgcn_global_load_lds((glb_u32*)(uintptr_t)g,
                                   (lds_u32*)(unsigned int)(uintptr_t)l,
                                   16, 0, 0);
}

__global__
__attribute__((amdgpu_flat_work_group_size(1024, 1024)))
void sfnn_fused(
    const float* __restrict__ x, const float* __restrict__ Wb,
    const float* __restrict__ bb, const float* __restrict__ Wo,
    const float* __restrict__ bo, const float* __restrict__ tau_m,
    const float* __restrict__ tau_n, float* __restrict__ out)
{
  const int b    = blockIdx.x;
  const int tid  = threadIdx.x;
  const int lane = tid & 63;
  const int w    = tid >> 6;          // wave id 0..15
  const int l16  = lane & 15;
  const int lhi  = lane >> 4;

  // LDS: 48K Xraw(f32,3buf) + 16K Xb(bf16,2buf) + 32K DfT + 16K Mb + 8K WoT = 120K
  __shared__ __align__(16) float          Xraw[3][TT * INt];   // DMA target, linear
  __shared__ __align__(16) unsigned char  Xb[2][TT * 256];     // bf16, swizzled
  __shared__ __align__(16) float          DfT[Ht * TT];        // D^T [h][t], swizzled
  __shared__ __align__(16) unsigned short Mb[TT * Ht];         // m bf16 [t][h], swizzled
  __shared__ __align__(16) unsigned short WoT[16 * Ht];        // Wo^T bf16 [j][k], swizzled

  // scan params (threads 0..255: channel h = tid)
  const int   hch   = tid & 255;
  const float beta  = 1.f / (1.f + expf(-tau_n[hch]));
  const float alpha = 1.f / (1.f + expf(-tau_m[hch]));
  const float omb   = 1.f - beta;
  const float oma   = 1.f - alpha;
  const float bbh   = bb[hch];
  const float bo_l  = (l16 < OUTt) ? bo[l16] : 0.f;

  // ---- stage WoT: [j][k] bf16, rows j>=8 zero ----
  {
    const int j  = w;
    const int k0 = 4 * (tid & 63);
    float v0 = 0.f, v1 = 0.f, v2 = 0.f, v3 = 0.f;
    if (j < OUTt) {
      v0 = Wo[(k0 + 0) * OUTt + j]; v1 = Wo[(k0 + 1) * OUTt + j];
      v2 = Wo[(k0 + 2) * OUTt + j]; v3 = Wo[(k0 + 3) * OUTt + j];
    }
    unsigned long long pk = (unsigned long long)pack2(v0, v1) |
                            ((unsigned long long)pack2(v2, v3) << 32);
    *(unsigned long long*)(&WoT[j * 256 + (k0 ^ ((j & 7) << 3))]) = pk;
  }

  // ---- branch weights: GEMM waves 0-7, wave owns h in [32w, 32w+32) ----
  Frag Wf[2][4];                      // [16-col half][k-step] = 32 VGPRs
  if (w < 8) {
    #pragma unroll
    for (int nh = 0; nh < 2; ++nh) {
      const int h = 32 * w + 16 * nh + l16;
      const int n = h >> 6, s = h & 63;
      #pragma unroll
      for (int ks = 0; ks < 4; ++ks) {
        #pragma unroll
        for (int j = 0; j < 8; ++j) {
          const int i = 32 * ks + 8 * lhi + j;
          Wf[nh][ks].s[j] = (short)f2bf(Wb[(n * 128 + i) * 64 + s]);
        }
      }
    }
  }

  const float* xb   = x   + (size_t)b * Tt * INt;
  float*       outb = out + (size_t)b * Tt * OUTt;

  float c_s = 0.f, m_s = 0.f;
  f32x4 dacc[2][2];                   // [tt][nh], live across barriers

  #define BAR() do {                                                       \
    asm volatile("s_waitcnt lgkmcnt(0)" ::: "memory");                     \
    __builtin_amdgcn_s_barrier();                                          \
  } while (0)

  #define WAITVM(N) do {                                                   \
    asm volatile("s_waitcnt vmcnt(" #N ")" ::: "memory");                  \
    __builtin_amdgcn_sched_barrier(0);                                     \
  } while (0)

  // stager waves 12-15: 4 DMA chunks of 1KB each (tile = 16KB f32, linear)
  #define ISSUE_DMA(TILE) do {                                             \
    const int _bi = (TILE) % 3;                                            \
    const float* _gs = xb + (size_t)(TILE) * (TT * INt);                   \
    _Pragma("unroll")                                                      \
    for (int q = 0; q < 4; ++q) {                                          \
      const int c = (w - 12) * 4 + q;                                      \
      dma16(_gs + c * 256 + lane * 4, &Xraw[_bi][c * 256]);                \
    }                                                                      \
  } while (0)

  // waves 12-15: f32 Xraw -> swizzled bf16 Xb.
  // RACE FIX (r7): each wave converts EXACTLY the chunks it DMA'd
  // (c = 4*(w-12)+q), so its own vmcnt wait covers everything it reads.
  // chunk c = floats [256c, 256c+256) = rows t = 2c, 2c+1;
  // lane reads f32x4 at 256c + 4*lane -> t = 2c + (lane>>5), k = 4*(lane&31).
  #define CONVERT(TILE) do {                                               \
    const int _bi = (TILE) % 3;                                            \
    const int _bo = (TILE) & 1;                                            \
    const int i8  = 8 * (lane & 31);    /* byte col base = 2*k */          \
    _Pragma("unroll")                                                      \
    for (int q = 0; q < 4; ++q) {                                          \
      const int c = (w - 12) * 4 + q;                                      \
      const int t = 2 * c + (lane >> 5);                                   \
      f32x4 v = *(const f32x4*)(&Xraw[_bi][256 * c + 4 * lane]);           \
      unsigned long long pk = (unsigned long long)pack2(v[0], v[1]) |      \
            ((unsigned long long)pack2(v[2], v[3]) << 32);                 \
      *(unsigned long long*)(&Xb[_bo][t * 256 + (i8 ^ ((t & 7) << 4))]) = pk; \
    }                                                                      \
  } while (0)

  // waves 0-7: D[t 0..32)[h 32w..32w+32), K=128
  #define GEMM(BUF) do {                                                   \
    _Pragma("unroll")                                                      \
    for (int tt = 0; tt < 2; ++tt) {                                       \
      const int row = 16 * tt + l16;                                       \
      const int rs = row * 256, sw = (row & 7) << 4;                       \
      _Pragma("unroll")                                                    \
      for (int ks = 0; ks < 4; ++ks) {                                     \
        Frag a;                                                            \
        a.u = *(const u32x4*)(&Xb[BUF][rs + ((64 * ks + 16 * lhi) ^ sw)]); \
        _Pragma("unroll")                                                  \
        for (int nh = 0; nh < 2; ++nh)                                     \
          dacc[tt][nh] = __builtin_amdgcn_mfma_f32_16x16x32_bf16(          \
              a.b, Wf[nh][ks].b, dacc[tt][nh], 0, 0, 0);                   \
      }                                                                    \
    }                                                                      \
  } while (0)

  #define GEMMZ(BUF) do {                                                  \
    _Pragma("unroll")                                                      \
    for (int tt = 0; tt < 2; ++tt)                                         \
      _Pragma("unroll")                                                    \
      for (int nh = 0; nh < 2; ++nh) dacc[tt][nh] = f32x4{0.f,0.f,0.f,0.f};\
    GEMM(BUF);                                                             \
  } while (0)

  // dacc -> DfT[h][t] b128 (4 consecutive t), granule XOR (h&7)
  #define WRITEDF() do {                                                   \
    _Pragma("unroll")                                                      \
    for (int tt = 0; tt < 2; ++tt)                                         \
      _Pragma("unroll")                                                    \
      for (int nh = 0; nh < 2; ++nh) {                                     \
        const int h = 32 * w + 16 * nh + l16;                              \
        *(f32x4*)(&DfT[h * 32 + ((((4 * tt + lhi)) ^ (h & 7)) << 2)]) =    \
            dacc[tt][nh];                                                  \
      }                                                                    \
  } while (0)

  // threads 0..255: contiguous-row b128 reads + serial EMA + Mb writes
  #define SCAN() do {                                                      \
    if (tid < 256) {                                                       \
      const int hb = tid * 32, hs = tid & 7;                               \
      _Pragma("unroll")                                                    \
      for (int gg = 0; gg < 2; ++gg) {                                     \
        f32x4 dv[4];                                                       \
        _Pragma("unroll")                                                  \
        for (int q = 0; q < 4; ++q)                                        \
          dv[q] = *(const f32x4*)(&DfT[hb + (((4 * gg + q) ^ hs) << 2)]);  \
        _Pragma("unroll")                                                  \
        for (int q = 0; q < 4; ++q)                                        \
          _Pragma("unroll")                                                \
          for (int r = 0; r < 4; ++r) {                                    \
            const int t = 16 * gg + 4 * q + r;                             \
            const float d = dv[q][r] + bbh;                                \
            c_s = fmaf(beta, c_s, omb * d);                                \
            m_s = fmaf(alpha, m_s, oma * c_s);                             \
            Mb[t * 256 + (tid ^ ((t & 7) << 3))] = f2bf(m_s);              \
          }                                                                \
      }                                                                    \
    }                                                                      \
  } while (0)

  // waves 8-9: rows [16pw,16pw+16), full K=256, sigmoid + store (tile TI)
  #define PROJ(TI) do {                                                    \
    const int pw = w - 8;                                                  \
    const int trow = 16 * pw + l16;                                        \
    const int mrb = trow * 256, msw = (trow & 7) << 3;                     \
    const int wrb = l16 * 256,  wsw = (l16 & 7) << 3;                      \
    f32x4 p = f32x4{0.f, 0.f, 0.f, 0.f};                                   \
    _Pragma("unroll")                                                      \
    for (int ks = 0; ks < 8; ++ks) {                                       \
      const int k0 = 32 * ks + 8 * lhi;                                    \
      Frag ma, wo;                                                         \
      ma.u = *(const u32x4*)(&Mb[mrb + (k0 ^ msw)]);                       \
      wo.u = *(const u32x4*)(&WoT[wrb + (k0 ^ wsw)]);                      \
      p = __builtin_amdgcn_mfma_f32_16x16x32_bf16(ma.b, wo.b, p, 0, 0, 0); \
    }                                                                      \
    if (l16 < OUTt) {                                                      \
      _Pragma("unroll")                                                    \
      for (int r = 0; r < 4; ++r) {                                        \
        const int t = 16 * pw + 4 * lhi + r;                               \
        outb[(size_t)((TI) * TT + t) * OUTt + l16] =                       \
            1.f / (1.f + __expf(-(p[r] + bo_l)));                          \
      }                                                                    \
    }                                                                      \
  } while (0)

  // ---------------- prologue ----------------
  if (w >= 12) {
    ISSUE_DMA(0); ISSUE_DMA(1); ISSUE_DMA(2);   // 12 loads in flight
    WAITVM(8);                                  // own tile-0 chunks landed
    CONVERT(0);
    asm volatile("s_waitcnt lgkmcnt(0)" ::: "memory");  // reads done pre-reissue
    ISSUE_DMA(3);                               // 12 in flight again
    WAITVM(8);                                  // own tile-1 chunks landed
    CONVERT(1);
  }
  BAR();                                        // Xb[0], Xb[1], WoT visible
  if (w < 8) GEMMZ(0);                          // dacc = D(0)

  // ---------------- pipeline ----------------
  // iter I:  A: WRITEDF(I) | PROJ(I-1) | GEMM(I+1)       (Xb[(I+1)&1])
  //          B1
  //          B: SCAN(I) | ISSUE(I+4), wait tile I+2, CONVERT(I+2)
  //          B2
  #define ITER(I, DOPROJ, DOGEMM, DOISS, DOCONV, WAITSTMT) do {            \
    if (w < 8) {                                                           \
      WRITEDF();                                                           \
      if (DOGEMM) GEMMZ(((I) + 1) & 1);                                    \
    } else if (DOPROJ && w < 10) {                                         \
      PROJ((I) - 1);                                                       \
    }                                                                      \
    BAR();            /* B1 */                                             \
    SCAN();                                                                \
    if (w >= 12) {                                                         \
      if (DOISS) ISSUE_DMA((I) + 4);                                       \
      WAITSTMT;                                                            \
      if (DOCONV) CONVERT((I) + 2);                                        \
    }                                                                      \
    BAR();            /* B2 */                                             \
  } while (0)

  ITER(0, 0, 1, 1, 1, WAITVM(8));
  for (int I = 1; I <= 59; ++I) {
    ITER(I, 1, 1, 1, 1, WAITVM(8));
  }
  ITER(60, 1, 1, 0, 1, WAITVM(4));
  ITER(61, 1, 1, 0, 1, WAITVM(0));
  ITER(62, 1, 1, 0, 0, (void)0);
  ITER(63, 1, 0, 0, 0, (void)0);
  if (w >= 8 && w < 10) PROJ(63);

  #undef ISSUE_DMA
  #undef CONVERT
  #undef GEMM
  #undef GEMMZ
  #undef WRITEDF
  #undef SCAN
  #undef PROJ
  #undef ITER
  #undef BAR
  #undef WAITVM
}

extern "C" void kernel_launch(void* const* d_in, const int* in_sizes, int n_in,
                              void* d_out, int out_size, void* d_ws, size_t ws_size,
                              hipStream_t stream) {
  const float* x     = (const float*)d_in[0];
  const float* Wb    = (const float*)d_in[1];
  const float* bb    = (const float*)d_in[2];
  const float* Wo    = (const float*)d_in[3];
  const float* bo    = (const float*)d_in[4];
  const float* tau_m = (const float*)d_in[5];
  const float* tau_n = (const float*)d_in[6];
  float* out = (float*)d_out;

  sfnn_fused<<<dim3(256), dim3(1024), 0, stream>>>(x, Wb, bb, Wo, bo, tau_m, tau_n, out);
}

// Round 9
// 140.452 us; speedup vs baseline: 1.2744x; 1.2744x over previous
//
#include <hip/hip_runtime.h>
#include <hip/hip_bf16.h>
#include <math.h>

#define DEVFN __device__ __forceinline__

typedef __attribute__((ext_vector_type(8))) __bf16 bf16x8;
typedef __attribute__((ext_vector_type(8))) short s16x8;
typedef __attribute__((ext_vector_type(4))) float f32x4;
typedef __attribute__((ext_vector_type(16))) float f32x16;
typedef __attribute__((ext_vector_type(4))) unsigned int u32x4;

constexpr int Tt    = 2048;
constexpr int INt   = 128;
constexpr int Ht    = 256;
constexpr int OUTt  = 8;
constexpr int TT    = 64;           // time tile
constexpr int NTILE = 32;

union Frag {
  s16x8 s;
  bf16x8 b;
  u32x4 u;
};

DEVFN unsigned short f2bf(float f) {
  unsigned int u = __builtin_bit_cast(unsigned int, f);
  u += 0x7fffu + ((u >> 16) & 1u);   // round-to-nearest-even
  return (unsigned short)(u >> 16);
}

DEVFN unsigned int pack2(float lo, float hi) {
  return (unsigned int)f2bf(lo) | ((unsigned int)f2bf(hi) << 16);
}

__global__
__attribute__((amdgpu_flat_work_group_size(1024, 1024)))
void sfnn_fused(
    const float* __restrict__ x, const float* __restrict__ Wb,
    const float* __restrict__ bb, const float* __restrict__ Wo,
    const float* __restrict__ bo, const float* __restrict__ tau_m,
    const float* __restrict__ tau_n, float* __restrict__ out)
{
  const int b    = blockIdx.x;
  const int tid  = threadIdx.x;
  const int lane = tid & 63;
  const int w    = tid >> 6;          // wave id 0..15
  const int l16  = lane & 15;
  const int lhi  = lane >> 4;
  const int l32  = lane & 31;
  const int uh   = lane >> 5;         // k-half / t-half selector
  const int sid  = tid - 512;         // stager index (waves 8-15)

  // LDS: 32K Xb + 64K Mb + 8K WoT = 104KB
  __shared__ __align__(16) unsigned char  Xb[2][TT * 256];   // bf16 x, swizzled
  __shared__ __align__(16) unsigned short Mb[2][TT * 256];   // m bf16 [t][h], swizzled
  __shared__ __align__(16) unsigned short WoT[16 * 256];     // Wo^T bf16 [j][k], swizzled

  // ---- stage WoT: [j][k] bf16, rows j>=8 zero ----
  {
    const int j  = w;
    const int k0 = 4 * (tid & 63);
    float v0 = 0.f, v1 = 0.f, v2 = 0.f, v3 = 0.f;
    if (j < OUTt) {
      v0 = Wo[(k0 + 0) * OUTt + j]; v1 = Wo[(k0 + 1) * OUTt + j];
      v2 = Wo[(k0 + 2) * OUTt + j]; v3 = Wo[(k0 + 3) * OUTt + j];
    }
    unsigned long long pk = (unsigned long long)pack2(v0, v1) |
                            ((unsigned long long)pack2(v2, v3) << 32);
    *(unsigned long long*)(&WoT[j * 256 + (k0 ^ ((j & 7) << 3))]) = pk;
  }

  // ---- scan params: GEMM wave w<8, lane owns channel ch = 32w + l32 ----
  const int   ch    = (32 * w + l32) & 255;   // masked so w>=8 stays in-bounds
  const float beta  = 1.f / (1.f + expf(-tau_n[ch]));
  const float alpha = 1.f / (1.f + expf(-tau_m[ch]));
  const float omb   = 1.f - beta;
  const float oma   = 1.f - alpha;
  const float bbh   = bb[ch];
  const float bo_l  = (l16 < OUTt) ? bo[l16] : 0.f;

  // ---- branch weights (B operand, 32x32x16): wave w<8 owns h in [32w,32w+32) ----
  // B[k][n]: lane&31 = n = h, k = 16ks + 8*uh + j
  Frag Wf[8];
  if (w < 8) {
    const int n = ch >> 6, s = ch & 63;
    #pragma unroll
    for (int ks = 0; ks < 8; ++ks) {
      #pragma unroll
      for (int j = 0; j < 8; ++j) {
        const int i = 16 * ks + 8 * uh + j;
        Wf[ks].s[j] = (short)f2bf(Wb[(n * 128 + i) * 64 + s]);
      }
    }
  }

  const float* xb   = x   + (size_t)b * Tt * INt;
  float*       outb = out + (size_t)b * Tt * OUTt;

  float  c_s = 0.f, m_s = 0.f;        // in-register EMA state (GEMM waves)
  f32x16 dacc;                        // 32x32 D accumulator (one t-tile)
  f32x4  QA0, QA1, QA2, QA3;          // stager prefetch set A (even tiles)
  f32x4  QB0, QB1, QB2, QB3;          // stager prefetch set B (odd tiles)

  #define BAR() do {                                                       \
    asm volatile("s_waitcnt lgkmcnt(0)" ::: "memory");                     \
    __builtin_amdgcn_s_barrier();                                          \
  } while (0)

  #define WAITVM(N) do {                                                   \
    asm volatile("s_waitcnt vmcnt(" #N ")" ::: "memory");                  \
    __builtin_amdgcn_sched_barrier(0);                                     \
  } while (0)

  // stager waves 8-15: 4 asm-pinned 16B loads; tile = 8192 floats, rounds of 2048
  #define ISSUE(TILE, Q0, Q1, Q2, Q3) do {                                 \
    const float* _p = xb + (size_t)(TILE) * (TT * INt) + 4 * (size_t)sid;  \
    asm volatile("global_load_dwordx4 %0, %1, off" : "=&v"(Q0) : "v"(_p));        \
    asm volatile("global_load_dwordx4 %0, %1, off" : "=&v"(Q1) : "v"(_p + 2048)); \
    asm volatile("global_load_dwordx4 %0, %1, off" : "=&v"(Q2) : "v"(_p + 4096)); \
    asm volatile("global_load_dwordx4 %0, %1, off" : "=&v"(Q3) : "v"(_p + 6144)); \
  } while (0)

  // pack f32->bf16 into swizzled Xb; round q: f = 2048q+4sid -> t = 16q+(sid>>5)
  #define STAGE(BUF, Q0, Q1, Q2, Q3) do {                                  \
    const int kb = 8 * (sid & 31);                                         \
    f32x4 qq[4] = {Q0, Q1, Q2, Q3};                                        \
    _Pragma("unroll")                                                      \
    for (int q = 0; q < 4; ++q) {                                          \
      const int t = 16 * q + (sid >> 5);                                   \
      unsigned long long pk = (unsigned long long)pack2(qq[q][0], qq[q][1]) |  \
            ((unsigned long long)pack2(qq[q][2], qq[q][3]) << 32);         \
      *(unsigned long long*)(&Xb[BUF][t * 256 + (kb ^ ((t & 7) << 4))]) = pk;  \
    }                                                                      \
  } while (0)

  // GEMM half: D[t = 32*HH .. +32)[h = 32w .. +32), K=128 via 8x mfma 32x32x16
  // A[m][k]: lane&31 = m = t-row, k = 16ks + 8*uh (16B read)
  #define GEMMH(BUF, HH) do {                                              \
    _Pragma("unroll")                                                      \
    for (int ri = 0; ri < 16; ++ri) dacc[ri] = 0.f;                        \
    const int row = 32 * (HH) + l32;                                       \
    const int rs = row * 256, sw = (row & 7) << 4;                         \
    _Pragma("unroll")                                                      \
    for (int ks = 0; ks < 8; ++ks) {                                       \
      Frag a;                                                              \
      a.u = *(const u32x4*)(&Xb[BUF][rs + ((32 * ks + 16 * uh) ^ sw)]);    \
      dacc = __builtin_amdgcn_mfma_f32_32x32x16_bf16(a.b, Wf[ks].b, dacc, 0, 0, 0); \
    }                                                                      \
  } while (0)

  // in-register scan over this half's 32 t-steps.
  // C/D 32x32 layout: col = lane&31 (= h), row(t') = (reg&3) + 8*(reg>>2) + 4*uh.
  // Segment j covers t' = 4j..4j+3, all in half uh == j&1; reg = r + 4*(j>>1).
  // State ping-pongs between halves via shfl_xor 32 before each segment.
  #define SCANH(MBUF, HH) do {                                             \
    _Pragma("unroll")                                                      \
    for (int j = 0; j < 8; ++j) {                                          \
      c_s = __shfl_xor(c_s, 32);                                           \
      m_s = __shfl_xor(m_s, 32);                                           \
      const bool act = (uh == ((j) & 1));                                  \
      _Pragma("unroll")                                                    \
      for (int r = 0; r < 4; ++r) {                                        \
        const float d = dacc[r + 4 * ((j) >> 1)] + bbh;                    \
        c_s = fmaf(beta, c_s, omb * d);                                    \
        m_s = fmaf(alpha, m_s, oma * c_s);                                 \
        if (act) {                                                         \
          const int t = 32 * (HH) + 4 * (j) + r;                           \
          Mb[MBUF][t * 256 + (ch ^ ((t & 7) << 3))] = f2bf(m_s);           \
        }                                                                  \
      }                                                                    \
    }                                                                      \
  } while (0)

  // waves 8-9: 2 row-blocks of 16, full K=256, sigmoid + store (tile TI)
  #define PROJ(TI, MBUF) do {                                              \
    _Pragma("unroll")                                                      \
    for (int blk = 0; blk < 2; ++blk) {                                    \
      const int pw2 = 2 * (w - 8) + blk;                                   \
      const int trow = 16 * pw2 + l16;                                     \
      const int mrb = trow * 256, msw = (trow & 7) << 3;                   \
      const int wrb = l16 * 256,  wsw = (l16 & 7) << 3;                    \
      f32x4 p = f32x4{0.f, 0.f, 0.f, 0.f};                                 \
      _Pragma("unroll")                                                    \
      for (int ks = 0; ks < 8; ++ks) {                                     \
        const int k0 = 32 * ks + 8 * lhi;                                  \
        Frag ma, wo;                                                       \
        ma.u = *(const u32x4*)(&Mb[MBUF][mrb + (k0 ^ msw)]);               \
        wo.u = *(const u32x4*)(&WoT[wrb + (k0 ^ wsw)]);                    \
        p = __builtin_amdgcn_mfma_f32_16x16x32_bf16(ma.b, wo.b, p, 0, 0, 0); \
      }                                                                    \
      if (l16 < OUTt) {                                                    \
        _Pragma("unroll")                                                  \
        for (int r = 0; r < 4; ++r) {                                      \
          const int t = 16 * pw2 + 4 * lhi + r;                            \
          outb[(size_t)((TI) * TT + t) * OUTt + l16] =                     \
              1.f / (1.f + __expf(-(p[r] + bo_l)));                        \
        }                                                                  \
      }                                                                    \
    }                                                                      \
  } while (0)

  // ---------------- prologue ----------------
  if (w >= 8) {
    ISSUE(0, QA0, QA1, QA2, QA3);     // tile 0 -> set A
    ISSUE(1, QB0, QB1, QB2, QB3);     // tile 1 -> set B
    WAITVM(4);                        // tile 0 landed
    STAGE(0, QA0, QA1, QA2, QA3);     // Xb[0]
  }
  BAR();

  // ---------------- single-barrier pipeline ----------------
  // iter I: {GEMM+scan(I) on Xb[I&1] -> Mb[I&1]} || {PROJ(I-1) from Mb[(I-1)&1];
  //          ISSUE(I+2); WAITVM; STAGE(I+1) -> Xb[(I+1)&1]}  then one BAR.
  // PROJ before ISSUE so its global stores drain before the counted wait.
  #define ITER_EV(I, DOPROJ, DOISS, DOWAIT, WN, DOSTG) do {                \
    if (w < 8) {                                                           \
      GEMMH((I) & 1, 0); SCANH((I) & 1, 0);                                \
      GEMMH((I) & 1, 1); SCANH((I) & 1, 1);                                \
    } else {                                                               \
      if (DOPROJ && w < 10) PROJ((I) - 1, ((I) - 1) & 1);                  \
      if (DOISS) ISSUE((I) + 2, QA0, QA1, QA2, QA3);                       \
      if (DOWAIT) WAITVM(WN);                                              \
      if (DOSTG) STAGE(1, QB0, QB1, QB2, QB3);                             \
    }                                                                      \
    BAR();                                                                 \
  } while (0)

  #define ITER_OD(I, DOPROJ, DOISS, DOWAIT, WN, DOSTG) do {                \
    if (w < 8) {                                                           \
      GEMMH((I) & 1, 0); SCANH((I) & 1, 0);                                \
      GEMMH((I) & 1, 1); SCANH((I) & 1, 1);                                \
    } else {                                                               \
      if (DOPROJ && w < 10) PROJ((I) - 1, ((I) - 1) & 1);                  \
      if (DOISS) ISSUE((I) + 2, QB0, QB1, QB2, QB3);                       \
      if (DOWAIT) WAITVM(WN);                                              \
      if (DOSTG) STAGE(0, QA0, QA1, QA2, QA3);                             \
    }                                                                      \
    BAR();                                                                 \
  } while (0)

  ITER_EV(0, 0, 1, 1, 4, 1);                       // issue 2->A, stage 1->Xb[1]
  for (int ii = 0; ii < 14; ++ii) {
    ITER_OD(2 * ii + 1, 1, 1, 1, 4, 1);            // issue odd->B, stage even->Xb[0]
    ITER_EV(2 * ii + 2, 1, 1, 1, 4, 1);            // issue even->A, stage odd->Xb[1]
  }
  ITER_OD(29, 1, 1, 1, 4, 1);                      // issue 31->B, stage 30->Xb[0]
  ITER_EV(30, 1, 0, 1, 0, 1);                      // drain, stage 31->Xb[1]
  ITER_OD(31, 1, 0, 0, 0, 0);                      // PROJ(30) only
  if (w >= 8 && w < 10) PROJ(31, 1);

  #undef ISSUE
  #undef STAGE
  #undef GEMMH
  #undef SCANH
  #undef PROJ
  #undef ITER_EV
  #undef ITER_OD
  #undef BAR
  #undef WAITVM
}

extern "C" void kernel_launch(void* const* d_in, const int* in_sizes, int n_in,
                              void* d_out, int out_size, void* d_ws, size_t ws_size,
                              hipStream_t stream) {
  const float* x     = (const float*)d_in[0];
  const float* Wb    = (const float*)d_in[1];
  const float* bb    = (const float*)d_in[2];
  const float* Wo    = (const float*)d_in[3];
  const float* bo    = (const float*)d_in[4];
  const float* tau_m = (const float*)d_in[5];
  const float* tau_n = (const float*)d_in[6];
  float* out = (float*)d_out;

  sfnn_fused<<<dim3(256), dim3(1024), 0, stream>>>(x, Wb, bb, Wo, bo, tau_m, tau_n, out);
}